// Round 5
// baseline (35.774 us; speedup 1.0000x reference)
//
#include <hip/hip_runtime.h>
#include <math.h>

#define NP 256      // ids_per_batch
#define NK 16       // imgs_per_id
#define ND 2048     // feature_dim
#define MARGIN 10.0f
#define EPSV 1e-12f
#define NBLK_B 256  // blocks in kernel B

typedef short bf16x8 __attribute__((ext_vector_type(8)));   // 8 bf16 (4 VGPRs)
typedef float f32x4 __attribute__((ext_vector_type(4)));    // MFMA C/D

static __device__ __forceinline__ unsigned short f2bf(float f) {
  unsigned u = __float_as_uint(f);
  return (unsigned short)((u + 0x7fffu + ((u >> 16) & 1u)) >> 16);  // RNE
}

// ---------------------------------------------------------------------------
// A: block p -> center_p (bf16), cc_p, intra_max_p; init inter=+inf; zero
// ticket. 1024 threads (16 waves/CU), each owns one float2 column pair.
// ---------------------------------------------------------------------------
__global__ __launch_bounds__(1024) void k_center_intra(
    const float* __restrict__ F, unsigned short* __restrict__ Cb,
    float* __restrict__ cc, int* __restrict__ ticket,
    float* __restrict__ out) {
  const int p = blockIdx.x;
  const int t = threadIdx.x;
  const int wave = t >> 6, lane = t & 63;
  const int d = t * 2;

  float2 x[NK];
#pragma unroll
  for (int k = 0; k < NK; ++k)
    x[k] = *reinterpret_cast<const float2*>(&F[((size_t)(p * NK + k)) * ND + d]);
#pragma unroll
  for (int k = 0; k < NK; ++k)
    asm volatile("" : "+v"(x[k].x), "+v"(x[k].y));

  float2 c;
  c.x = c.y = 0.f;
#pragma unroll
  for (int k = 0; k < NK; ++k) { c.x += x[k].x; c.y += x[k].y; }
  const float inv = 1.0f / 16.0f;
  c.x *= inv; c.y *= inv;

  ushort2 cb;
  cb.x = f2bf(c.x); cb.y = f2bf(c.y);
  *reinterpret_cast<ushort2*>(&Cb[(size_t)p * ND + d]) = cb;

  float ccp = c.x * c.x + c.y * c.y;

  float acc[NK];
#pragma unroll
  for (int k = 0; k < NK; ++k) {
    float dx = x[k].x - c.x, dy = x[k].y - c.y;
    acc[k] = dx * dx + dy * dy;
  }

#pragma unroll
  for (int k = 0; k < NK; ++k) {
    float v = acc[k];
#pragma unroll
    for (int m = 32; m > 0; m >>= 1) v += __shfl_xor(v, m);
    acc[k] = v;
  }
  {
    float v = ccp;
#pragma unroll
    for (int m = 32; m > 0; m >>= 1) v += __shfl_xor(v, m);
    ccp = v;
  }

  __shared__ float red[16][NK + 2];
  if (lane == 0) {
#pragma unroll
    for (int k = 0; k < NK; ++k) red[wave][k] = acc[k];
    red[wave][NK] = ccp;
  }
  __syncthreads();
  if (t < NK + 1) {
    float s = 0.f;
#pragma unroll
    for (int w = 0; w < 16; ++w) s += red[w][t];
    if (t == NK) {
      cc[p] = s;
    } else {
      float v = sqrtf(fmaxf(s, EPSV));
#pragma unroll
      for (int m = 8; m > 0; m >>= 1) v = fmaxf(v, __shfl_xor(v, m));
      if (t == 0) out[1 + p] = v;  // intra_max
    }
  }
  if (t == 0) {
    reinterpret_cast<int*>(out)[1 + NP + p] = 0x7f800000;  // +inf
    if (p == 0) atomicExch(ticket, 0);
  }
}

// ---------------------------------------------------------------------------
// B: 256 blocks x 4 waves; block b -> 16x16 G-tile (pi=b>>4, qi=b&15),
// wave w -> K-slice [w*512, w*512+512) (16 MFMAs, 4 chains), LDS combine,
// fused inter_min atomicMin; last block (ticket) computes the loss.
// ---------------------------------------------------------------------------
__global__ __launch_bounds__(256) void k_pair_loss(
    const unsigned short* __restrict__ Cb, const float* __restrict__ cc,
    int* __restrict__ ticket, float* __restrict__ out) {
  const int b = blockIdx.x;
  const int t = threadIdx.x;
  const int wave = t >> 6, lane = t & 63;
  const int pi = b >> 4, qi = b & 15;
  const int lr = lane & 15;
  const int kg = (lane >> 4) * 8;

  const unsigned short* ap = &Cb[(size_t)(pi * 16 + lr) * ND + wave * 512 + kg];
  const unsigned short* bp = &Cb[(size_t)(qi * 16 + lr) * ND + wave * 512 + kg];

  f32x4 a0 = {0.f, 0.f, 0.f, 0.f}, a1 = a0, a2 = a0, a3 = a0;
#pragma unroll
  for (int i = 0; i < 4; ++i) {
    bf16x8 av0 = *reinterpret_cast<const bf16x8*>(ap + i * 128);
    bf16x8 bv0 = *reinterpret_cast<const bf16x8*>(bp + i * 128);
    bf16x8 av1 = *reinterpret_cast<const bf16x8*>(ap + i * 128 + 32);
    bf16x8 bv1 = *reinterpret_cast<const bf16x8*>(bp + i * 128 + 32);
    bf16x8 av2 = *reinterpret_cast<const bf16x8*>(ap + i * 128 + 64);
    bf16x8 bv2 = *reinterpret_cast<const bf16x8*>(bp + i * 128 + 64);
    bf16x8 av3 = *reinterpret_cast<const bf16x8*>(ap + i * 128 + 96);
    bf16x8 bv3 = *reinterpret_cast<const bf16x8*>(bp + i * 128 + 96);
    a0 = __builtin_amdgcn_mfma_f32_16x16x32_bf16(av0, bv0, a0, 0, 0, 0);
    a1 = __builtin_amdgcn_mfma_f32_16x16x32_bf16(av1, bv1, a1, 0, 0, 0);
    a2 = __builtin_amdgcn_mfma_f32_16x16x32_bf16(av2, bv2, a2, 0, 0, 0);
    a3 = __builtin_amdgcn_mfma_f32_16x16x32_bf16(av3, bv3, a3, 0, 0, 0);
  }
  f32x4 acc = a0 + a1 + a2 + a3;

  // split-K combine across the 4 waves via LDS
  __shared__ float red2[4][256];
#pragma unroll
  for (int r = 0; r < 4; ++r) red2[wave][lane * 4 + r] = acc[r];
  __syncthreads();

  {
    // t = lane*4 + r of the MFMA C layout: row=((t>>6)&3)*4+(t&3), col=(t>>2)&15
    float g = red2[0][t] + red2[1][t] + red2[2][t] + red2[3][t];
    const int row = ((t >> 6) & 3) * 4 + (t & 3);
    const int col = (t >> 2) & 15;
    const int p = pi * 16 + row, q = qi * 16 + col;
    const float cd2 = cc[p] + cc[q] - 2.0f * g;
    float cd = (p == q) ? INFINITY : sqrtf(fmaxf(cd2, EPSV));
#pragma unroll
    for (int m = 4; m <= 32; m <<= 1) cd = fminf(cd, __shfl_xor(cd, m));
    if (col == 0)
      atomicMin(reinterpret_cast<int*>(out) + 1 + NP + p, __float_as_int(cd));
  }

  // ---- last-block loss ----
  __syncthreads();
  __threadfence();
  __shared__ int my_ticket;
  if (t == 0) my_ticket = atomicAdd(ticket, 1);
  __syncthreads();
  if (my_ticket == NBLK_B - 1) {
    const float im = out[1 + t];  // written by kernel A
    const int bits = atomicOr(reinterpret_cast<int*>(out) + 1 + NP + t, 0);
    const float in_ = __int_as_float(bits);
    float v = fmaxf(im - in_ + MARGIN, 0.f);
#pragma unroll
    for (int m = 32; m > 0; m >>= 1) v += __shfl_xor(v, m);
    __shared__ float red3[4];
    if (lane == 0) red3[wave] = v;
    __syncthreads();
    if (t == 0) out[0] = (red3[0] + red3[1] + red3[2] + red3[3]) / (float)NP;
  }
}

// ---------------------------------------------------------------------------
extern "C" void kernel_launch(void* const* d_in, const int* in_sizes, int n_in,
                              void* d_out, int out_size, void* d_ws,
                              size_t ws_size, hipStream_t stream) {
  const float* F = (const float*)d_in[0];  // features [4096, 2048] fp32
  float* out = (float*)d_out;              // [513]: loss, intra_max, inter_min

  unsigned short* Cb = (unsigned short*)d_ws;  // 256*2048 bf16 (1 MB)
  float* cc = (float*)(Cb + (size_t)NP * ND);  // 256 fp32
  int* ticket = (int*)(cc + NP);               // 1 int

  k_center_intra<<<NP, 1024, 0, stream>>>(F, Cb, cc, ticket, out);
  k_pair_loss<<<NBLK_B, 256, 0, stream>>>(Cb, cc, ticket, out);
}